// Round 10
// baseline (668.572 us; speedup 1.0000x reference)
//
#include <hip/hip_runtime.h>

typedef __bf16  bf16x8 __attribute__((ext_vector_type(8)));
typedef float   f32x4  __attribute__((ext_vector_type(4)));
typedef float   f32x16 __attribute__((ext_vector_type(16)));
typedef unsigned int uint32x2 __attribute__((ext_vector_type(2)));

#define MFMA32(a,b,c) __builtin_amdgcn_mfma_f32_32x32x16_bf16((a),(b),(c),0,0,0)

template<int V> struct ic_t { static constexpr int value = V; };

// bf16 weight arena layout in d_ws (elements), Wt[n][k] with k padded
enum : int {
    OFF_W0 = 0,                      // [256][64]
    OFF_W1 = OFF_W0 + 256 * 64,      // [256][256]
    OFF_W2 = OFF_W1 + 256 * 256,
    OFF_W3 = OFF_W2 + 256 * 256,
    OFF_W4 = OFF_W3 + 256 * 256,     // [256][320]
    OFF_W5 = OFF_W4 + 256 * 320,
    OFF_W6 = OFF_W5 + 256 * 256,
    OFF_W7 = OFF_W6 + 256 * 256,
    OFF_WF = OFF_W7 + 256 * 256,     // [256][256]
    OFF_WD = OFF_WF + 256 * 256,     // [128][288]
    W_TOTAL = OFF_WD + 128 * 288
};

__device__ __forceinline__ unsigned short f2bf(float f) {
    unsigned int u = __float_as_uint(f);
    u += 0x7FFFu + ((u >> 16) & 1u);
    return (unsigned short)(u >> 16);
}

// Soft barrier: LDS ops visible + rendezvous; global loads stay in flight.
__device__ __forceinline__ void soft_barrier() {
    asm volatile("s_waitcnt lgkmcnt(0)" ::: "memory");
    __builtin_amdgcn_s_barrier();
}

__device__ __forceinline__ void prep_one(const float* __restrict__ src,
                                         unsigned short* __restrict__ dst,
                                         int fout, int Kp, int n1, int n2, int n3,
                                         int idx) {
    int n = idx / Kp;
    int k = idx - n * Kp;
    float v = 0.f;
    if (k < n1)                 v = src[k * fout + n];
    else if (k >= n2 && k < n3) v = src[(k - (n2 - n1)) * fout + n];
    dst[n * Kp + k] = f2bf(v);
}

__global__ void prep_kernel(const float* w0, const float* w1, const float* w2,
                            const float* w3, const float* w4, const float* w5,
                            const float* w6, const float* w7, const float* wf,
                            const float* wd, unsigned short* dst) {
    int i = blockIdx.x * 256 + threadIdx.x;
    if (i < 256 * 64)  { prep_one(w0, dst + OFF_W0, 256,  64,  63,  64,  64, i); return; }
    i -= 256 * 64;
    if (i < 256 * 256) { prep_one(w1, dst + OFF_W1, 256, 256, 256, 256, 256, i); return; }
    i -= 256 * 256;
    if (i < 256 * 256) { prep_one(w2, dst + OFF_W2, 256, 256, 256, 256, 256, i); return; }
    i -= 256 * 256;
    if (i < 256 * 256) { prep_one(w3, dst + OFF_W3, 256, 256, 256, 256, 256, i); return; }
    i -= 256 * 256;
    if (i < 256 * 320) { prep_one(w4, dst + OFF_W4, 256, 320,  63,  64, 320, i); return; }
    i -= 256 * 320;
    if (i < 256 * 256) { prep_one(w5, dst + OFF_W5, 256, 256, 256, 256, 256, i); return; }
    i -= 256 * 256;
    if (i < 256 * 256) { prep_one(w6, dst + OFF_W6, 256, 256, 256, 256, 256, i); return; }
    i -= 256 * 256;
    if (i < 256 * 256) { prep_one(w7, dst + OFF_W7, 256, 256, 256, 256, 256, i); return; }
    i -= 256 * 256;
    if (i < 256 * 256) { prep_one(wf, dst + OFF_WF, 256, 256, 256, 256, 256, i); return; }
    i -= 256 * 256;
    if (i < 128 * 288) { prep_one(wd, dst + OFF_WD, 128, 288, 286, 288, 288, i); return; }
}

struct Params {
    const float* x;
    const unsigned short* Wt;
    const float* b[8];
    const float* bfv;
    const float* bdv;
    const float* wsv;
    const float* bsv;
    const float* wrv;
    const float* brv;
    float* out;
};

// 64 rows/block, 4 waves, wave owns 64 output cols (CT=2 tiles of 32).
// mfma_f32_32x32x16_bf16: per K=16 step only 4 MFMA + 2 ds_read + 2 global
// (half the instruction count of the 16x16x32 version). Swapped operands:
// D[n][b] with col=lane&31 (batch), row=(reg&3)+8*(reg>>2)+4*(lane>>5)
// (neuron). Double-buffered Hs, 1 soft barrier/layer, depth-2 cross-layer
// weight prefetch. __launch_bounds__(256,2) -> VGPR cap 128 (arg2=4 caps 64!).
__global__ __launch_bounds__(256, 2) void nerf_kernel(Params P) {
    __shared__ char Hs0[32768];   // [64][256] bf16, swz ^((row&7)<<4)
    __shared__ char Hs1[32768];

    const int t    = threadIdx.x;
    const int lane = t & 63;
    const int wave = t >> 6;          // 0..3
    const int l31  = lane & 31;
    const int hi   = lane >> 5;       // 0..1
    const int hi8  = hi << 3;
    const int blockRow = blockIdx.x << 6;

    // ---- weight A-frag pipeline (persistent): aw0/aw1 = kt, kt+1
    bf16x8 aw0[2], aw1[2];
    {   // preload L0 kt0/kt1 (Kp=64, colbase wave*64)
        const unsigned short* Wb0 = P.Wt + OFF_W0 + (size_t)((wave << 6) + l31) * 64 + hi8;
#pragma unroll
        for (int ct = 0; ct < 2; ++ct) {
            aw0[ct] = *(const bf16x8*)(Wb0 + (size_t)(ct << 5) * 64);
            aw1[ct] = *(const bf16x8*)(Wb0 + (size_t)(ct << 5) * 64 + 16);
        }
    }

    // activation B-frag from GLOBAL x: batch = blockRow + rt*32 + l31,
    // k-elem j -> x col c0 + hi*8 + j, zero for c >= lim
    auto ldXg = [&](int rt, int c0, int lim) -> bf16x8 {
        const float* xr = P.x + (size_t)(blockRow + (rt << 5) + l31) * 93;
        bf16x8 r;
#pragma unroll
        for (int j = 0; j < 8; ++j) {
            int c = c0 + hi8 + j;
            r[j] = (c < lim) ? (__bf16)xr[c] : (__bf16)0.f;
        }
        return r;
    };
    // activation B-frag from Hs: row = rt*32 + l31, 16B contiguous k
    auto ldH = [&](const char* B, int rt, int kt) -> bf16x8 {
        int row = (rt << 5) + l31;
        int off = (row * 512 + (kt << 5) + (hi << 4)) ^ ((row & 7) << 4);
        return *(const bf16x8*)(B + off);
    };

    // GEMM layer. KT = K/16 steps, CT = col tiles/wave (2 -> 64 cols, 1 -> 32),
    // CTn = next layer's CT (0 = none). Entry: aw0/aw1 = this layer's kt0/kt1.
    // Exit: next layer's kt0/kt1 (loads in flight across the soft barrier).
    auto gemm = [&](auto KTt, auto CTt, auto CTnt, auto&& getB,
                    const unsigned short* W, int Kp, const float* bias, bool dorelu,
                    char* dst, const unsigned short* Wn, int Kpn, int cbn) {
        constexpr int KT  = decltype(KTt)::value;
        constexpr int CT  = decltype(CTt)::value;
        constexpr int CTn = decltype(CTnt)::value;
        const int cb = wave * (CT << 5);
        const unsigned short* Wb = W + (size_t)(cb + l31) * Kp + hi8;
        const unsigned short* Wbn = (CTn > 0) ? Wn + (size_t)(cbn + l31) * Kpn + hi8 : nullptr;

        // bias folded into acc init: neuron = cb + ct*32 + 8q + 4hi + e
        f32x16 acc[2][CT];
#pragma unroll
        for (int ct = 0; ct < CT; ++ct) {
            f32x16 ini;
#pragma unroll
            for (int q = 0; q < 4; ++q) {
                f32x4 bq = *(const f32x4*)(bias + cb + (ct << 5) + (q << 3) + (hi << 2));
#pragma unroll
                for (int e = 0; e < 4; ++e) ini[(q << 2) + e] = bq[e];
            }
            acc[0][ct] = ini;
            acc[1][ct] = ini;
        }

        bf16x8 bC[2], bN[2];
#pragma unroll
        for (int rt = 0; rt < 2; ++rt) { bC[rt] = getB(rt, 0); bN[rt] = bC[rt]; }

#pragma unroll
        for (int kt = 0; kt < KT; ++kt) {
            // depth-2 weight prefetch (wraps into next layer's kt0/kt1)
            bf16x8 awN[2];
            if (kt + 2 < KT) {
#pragma unroll
                for (int ct = 0; ct < CT; ++ct)
                    awN[ct] = *(const bf16x8*)(Wb + (size_t)(ct << 5) * Kp + ((kt + 2) << 4));
            } else if (CTn > 0) {
#pragma unroll
                for (int ct = 0; ct < (CTn > 0 ? CTn : 1); ++ct)
                    awN[ct] = *(const bf16x8*)(Wbn + (size_t)(ct << 5) * Kpn + ((kt + 2 - KT) << 4));
            } else {
#pragma unroll
                for (int ct = 0; ct < 2; ++ct) awN[ct] = aw1[ct];
            }
            // activation prefetch distance 1
            if (kt + 1 < KT) {
#pragma unroll
                for (int rt = 0; rt < 2; ++rt) bN[rt] = getB(rt, kt + 1);
            }
            __builtin_amdgcn_s_setprio(1);
#pragma unroll
            for (int ct = 0; ct < CT; ++ct) {
                acc[0][ct] = MFMA32(aw0[ct], bC[0], acc[0][ct]);
                acc[1][ct] = MFMA32(aw0[ct], bC[1], acc[1][ct]);
            }
            __builtin_amdgcn_s_setprio(0);
#pragma unroll
            for (int ct = 0; ct < 2; ++ct) { aw0[ct] = aw1[ct]; aw1[ct] = awN[ct]; }
#pragma unroll
            for (int rt = 0; rt < 2; ++rt) bC[rt] = bN[rt];
        }

        // epilogue: relu, cvt_pk to bf16, 4x b64 LDS writes per tile
#pragma unroll
        for (int ct = 0; ct < CT; ++ct) {
#pragma unroll
            for (int rt = 0; rt < 2; ++rt) {
                int row = (rt << 5) + l31;
                int rsw = (row & 7) << 4;
#pragma unroll
                for (int q = 0; q < 4; ++q) {
                    float v0 = acc[rt][ct][(q << 2) + 0];
                    float v1 = acc[rt][ct][(q << 2) + 1];
                    float v2 = acc[rt][ct][(q << 2) + 2];
                    float v3 = acc[rt][ct][(q << 2) + 3];
                    if (dorelu) {
                        v0 = fmaxf(v0, 0.f); v1 = fmaxf(v1, 0.f);
                        v2 = fmaxf(v2, 0.f); v3 = fmaxf(v3, 0.f);
                    }
                    unsigned int lo, hi2;
                    asm("v_cvt_pk_bf16_f32 %0, %1, %2" : "=v"(lo)  : "v"(v0), "v"(v1));
                    asm("v_cvt_pk_bf16_f32 %0, %1, %2" : "=v"(hi2) : "v"(v2), "v"(v3));
                    int col = cb + (ct << 5) + (q << 3) + (hi << 2);
                    int off = (row * 512 + (col << 1)) ^ rsw;
                    uint32x2 w2 = {lo, hi2};
                    *(uint32x2*)(dst + off) = w2;
                }
            }
        }
    };

    const unsigned short* Wt = P.Wt;
    char* cur = Hs0;
    char* alt = Hs1;

    // L0: K=64 from global x -> cur; next = W1
    gemm(ic_t<4>{}, ic_t<2>{}, ic_t<2>{},
         [&](int rt, int kt) { return ldXg(rt, kt << 4, 63); },
         Wt + OFF_W0, 64, P.b[0], true, cur, Wt + OFF_W1, 256, wave << 6);
    soft_barrier();

    // L1-3
    {
        const unsigned short* Wc[3] = {Wt + OFF_W1, Wt + OFF_W2, Wt + OFF_W3};
        const unsigned short* Wn[3] = {Wt + OFF_W2, Wt + OFF_W3, Wt + OFF_W4};
        const int Kpn[3] = {256, 256, 320};
        const float* bc[3] = {P.b[1], P.b[2], P.b[3]};
        for (int i = 0; i < 3; ++i) {
            gemm(ic_t<16>{}, ic_t<2>{}, ic_t<2>{},
                 [&](int rt, int kt) { return ldH(cur, rt, kt); },
                 Wc[i], 256, bc[i], true, alt, Wn[i], Kpn[i], wave << 6);
            soft_barrier();
            char* tmp = cur; cur = alt; alt = tmp;
        }
    }

    // L4: K=320 = [xyz(64) | h(256)]; next = W5
    gemm(ic_t<20>{}, ic_t<2>{}, ic_t<2>{},
         [&](int rt, int kt) { return (kt < 4) ? ldXg(rt, kt << 4, 63) : ldH(cur, rt, kt - 4); },
         Wt + OFF_W4, 320, P.b[4], true, alt, Wt + OFF_W5, 256, wave << 6);
    soft_barrier();
    { char* tmp = cur; cur = alt; alt = tmp; }

    // L5-7
    {
        const unsigned short* Wc[3] = {Wt + OFF_W5, Wt + OFF_W6, Wt + OFF_W7};
        const unsigned short* Wn[3] = {Wt + OFF_W6, Wt + OFF_W7, Wt + OFF_WF};
        const float* bc[3] = {P.b[5], P.b[6], P.b[7]};
        for (int i = 0; i < 3; ++i) {
            gemm(ic_t<16>{}, ic_t<2>{}, ic_t<2>{},
                 [&](int rt, int kt) { return ldH(cur, rt, kt); },
                 Wc[i], 256, bc[i], true, alt, Wn[i], 256, wave << 6);
            soft_barrier();
            char* tmp = cur; cur = alt; alt = tmp;
        }
    }
    // cur = h (layer-7 out)

    // sigma = h @ ws + bs (read-only on cur; WF writes alt -> no hazard)
    float sig;
    {
        int rr = t >> 2, q = t & 3;
        float sp = 0.f;
#pragma unroll
        for (int j = 0; j < 8; ++j) {
            int cb2 = (q << 6) + (j << 3);
            bf16x8 h8 = *(const bf16x8*)(cur + ((rr * 512 + (cb2 << 1)) ^ ((rr & 7) << 4)));
#pragma unroll
            for (int e = 0; e < 8; ++e) sp += (float)h8[e] * P.wsv[cb2 + e];
        }
        sp += __shfl_xor(sp, 1);
        sp += __shfl_xor(sp, 2);
        sig = sp + P.bsv[0];
    }

    // xyz_final = h @ wf + bf (no relu); next = WD (CT=1, Kp=288, cb=wave*32)
    gemm(ic_t<16>{}, ic_t<2>{}, ic_t<1>{},
         [&](int rt, int kt) { return ldH(cur, rt, kt); },
         Wt + OFF_WF, 256, P.bfv, false, alt, Wt + OFF_WD, 288, wave << 5);
    soft_barrier();
    { char* tmp = cur; cur = alt; alt = tmp; }
    // cur = xyz_final, alt = h (dead)

    // d = relu([xyz_final | dir] @ wd + bd): KT=18, CT=1 -> alt cols 0..127;
    // dir (x cols 63..92) read from global for kt 16,17
    gemm(ic_t<18>{}, ic_t<1>{}, ic_t<0>{},
         [&](int rt, int kt) {
             return (kt < 16) ? ldH(cur, rt, kt) : ldXg(rt, 63 + ((kt - 16) << 4), 93);
         },
         Wt + OFF_WD, 288, P.bdv, true, alt, nullptr, 0, 0);
    soft_barrier();

    // rgb = sigmoid(d @ wr + br); fused float4 store {r,g,b,sigma}
    {
        int rr = t >> 2, q = t & 3;
        float c0 = 0.f, c1 = 0.f, c2 = 0.f;
#pragma unroll
        for (int j = 0; j < 4; ++j) {
            int kb = (q << 5) + (j << 3);
            bf16x8 d8 = *(const bf16x8*)(alt + ((rr * 512 + (kb << 1)) ^ ((rr & 7) << 4)));
#pragma unroll
            for (int e = 0; e < 8; ++e) {
                float dv = (float)d8[e];
                const float* w = P.wrv + (kb + e) * 3;
                c0 += dv * w[0]; c1 += dv * w[1]; c2 += dv * w[2];
            }
        }
        c0 += __shfl_xor(c0, 1); c0 += __shfl_xor(c0, 2);
        c1 += __shfl_xor(c1, 1); c1 += __shfl_xor(c1, 2);
        c2 += __shfl_xor(c2, 1); c2 += __shfl_xor(c2, 2);
        if (q == 0) {
            float4 o;
            o.x = 1.f / (1.f + __expf(-(c0 + P.brv[0])));
            o.y = 1.f / (1.f + __expf(-(c1 + P.brv[1])));
            o.z = 1.f / (1.f + __expf(-(c2 + P.brv[2])));
            o.w = sig;
            ((float4*)P.out)[blockRow + rr] = o;
        }
    }
}

extern "C" void kernel_launch(void* const* d_in, const int* in_sizes, int n_in,
                              void* d_out, int out_size, void* d_ws, size_t ws_size,
                              hipStream_t stream) {
    const float* x = (const float*)d_in[0];
    const float* w[8];
    const float* b[8];
    for (int i = 0; i < 8; ++i) {
        w[i] = (const float*)d_in[1 + 2 * i];
        b[i] = (const float*)d_in[2 + 2 * i];
    }
    const float* wf  = (const float*)d_in[17];
    const float* bfv = (const float*)d_in[18];
    const float* wd  = (const float*)d_in[19];
    const float* bdv = (const float*)d_in[20];
    const float* wsv = (const float*)d_in[21];
    const float* bsv = (const float*)d_in[22];
    const float* wrv = (const float*)d_in[23];
    const float* brv = (const float*)d_in[24];

    unsigned short* Wt = (unsigned short*)d_ws;

    prep_kernel<<<(W_TOTAL + 255) / 256, 256, 0, stream>>>(
        w[0], w[1], w[2], w[3], w[4], w[5], w[6], w[7], wf, wd, Wt);

    Params P;
    P.x = x; P.Wt = Wt;
    for (int i = 0; i < 8; ++i) P.b[i] = b[i];
    P.bfv = bfv; P.bdv = bdv; P.wsv = wsv; P.bsv = bsv; P.wrv = wrv; P.brv = brv;
    P.out = (float*)d_out;

    nerf_kernel<<<262144 / 64, 256, 0, stream>>>(P);
}